// Round 2
// baseline (461.936 us; speedup 1.0000x reference)
//
#include <hip/hip_runtime.h>
#include <math.h>

#define NB 128
#define NM 64
#define NN 64
#define KSEL 3
#define SLOTS (NM * KSEL)          // 192
#define TOTSLOTS (NB * SLOTS)      // 24576
#define CONF_TH 0.05f
#define RAD2 0.01f                 // ACCEPTANCE_RADIUS^2
#define EPSV 1e-5

struct Ws {
  int   corr_n[TOTSLOTS];
  float corr_w[TOTSLOTS];
  float Rb[NB * 9];
  float tb[NB * 3];
  int   ncorr[NB];
  int   bestkey;
};

__device__ __forceinline__ void mat3vec(const double H[3][3], const double v[3], double o[3]) {
  o[0] = H[0][0] * v[0] + H[0][1] * v[1] + H[0][2] * v[2];
  o[1] = H[1][0] * v[0] + H[1][1] * v[1] + H[1][2] * v[2];
  o[2] = H[2][0] * v[0] + H[2][1] * v[1] + H[2][2] * v[2];
}

__device__ __forceinline__ void cross3(const double a[3], const double b[3], double o[3]) {
  o[0] = a[1] * b[2] - a[2] * b[1];
  o[1] = a[2] * b[0] - a[0] * b[2];
  o[2] = a[0] * b[1] - a[1] * b[0];
}

// acc[0]=S, acc[1..3]=Sum(w*ref), acc[4..6]=Sum(w*src), acc[7+c*3+d]=Sum(w*src_c*ref_d)
// Reproduces: wn = w/(S+eps); H = Sum wn (src-cs)(ref-cr)^T; H=USV^T; R=V diag(1,1,det) U^T
__device__ void solve_rigid(const double* acc, float* Rf, float* tf) {
  double denom = acc[0] + EPSV;
  double cr[3], cs[3];
  for (int i = 0; i < 3; i++) { cr[i] = acc[1 + i] / denom; cs[i] = acc[4 + i] / denom; }
  double sig = acc[0] / denom;
  double H[3][3];
  for (int c = 0; c < 3; c++)
    for (int d = 0; d < 3; d++)
      H[c][d] = acc[7 + c * 3 + d] / denom - (2.0 - sig) * cs[c] * cr[d];

  // A = H^T H (symmetric PSD, in ref-space)
  double A[3][3], V[3][3] = {{1,0,0},{0,1,0},{0,0,1}};
  for (int i = 0; i < 3; i++)
    for (int j = 0; j < 3; j++) {
      double s = 0;
      for (int k = 0; k < 3; k++) s += H[k][i] * H[k][j];
      A[i][j] = s;
    }
  // Cyclic Jacobi (fixed sweeps, deterministic)
  for (int sweep = 0; sweep < 15; sweep++) {
    for (int p = 0; p < 3; p++) {
      for (int q = p + 1; q < 3; q++) {
        double apq = A[p][q];
        if (fabs(apq) < 1e-300) continue;
        double tau = (A[q][q] - A[p][p]) / (2.0 * apq);
        double tt = (tau >= 0.0) ? 1.0 / (tau + sqrt(1.0 + tau * tau))
                                 : 1.0 / (tau - sqrt(1.0 + tau * tau));
        double c = 1.0 / sqrt(1.0 + tt * tt), s = tt * c;
        for (int k = 0; k < 3; k++) {      // A <- A*J
          double akp = A[k][p], akq = A[k][q];
          A[k][p] = c * akp - s * akq;
          A[k][q] = s * akp + c * akq;
        }
        for (int k = 0; k < 3; k++) {      // A <- J^T*A
          double apk = A[p][k], aqk = A[q][k];
          A[p][k] = c * apk - s * aqk;
          A[q][k] = s * apk + c * aqk;
        }
        for (int k = 0; k < 3; k++) {      // V <- V*J
          double vkp = V[k][p], vkq = V[k][q];
          V[k][p] = c * vkp - s * vkq;
          V[k][q] = s * vkp + c * vkq;
        }
      }
    }
  }
  double lam[3] = {A[0][0], A[1][1], A[2][2]};
  int i0 = 0, i1 = 1, i2 = 2, tmp;
  if (lam[i0] < lam[i1]) { tmp = i0; i0 = i1; i1 = tmp; }
  if (lam[i0] < lam[i2]) { tmp = i0; i0 = i2; i2 = tmp; }
  if (lam[i1] < lam[i2]) { tmp = i1; i1 = i2; i2 = tmp; }

  double v1[3] = {V[0][i0], V[1][i0], V[2][i0]};
  double v2[3] = {V[0][i1], V[1][i1], V[2][i1]};
  double u1[3], u2[3];
  mat3vec(H, v1, u1);
  double n1 = sqrt(u1[0]*u1[0] + u1[1]*u1[1] + u1[2]*u1[2]);
  if (n1 > 1e-30) { u1[0] /= n1; u1[1] /= n1; u1[2] /= n1; }
  else { u1[0] = 1; u1[1] = 0; u1[2] = 0; }
  mat3vec(H, v2, u2);
  double d12 = u1[0]*u2[0] + u1[1]*u2[1] + u1[2]*u2[2];
  u2[0] -= d12 * u1[0]; u2[1] -= d12 * u1[1]; u2[2] -= d12 * u1[2];
  double n2 = sqrt(u2[0]*u2[0] + u2[1]*u2[1] + u2[2]*u2[2]);
  if (n2 > 1e-30) { u2[0] /= n2; u2[1] /= n2; u2[2] /= n2; }
  else {
    double ax[3] = { (fabs(u1[0]) < 0.9) ? 1.0 : 0.0, (fabs(u1[0]) < 0.9) ? 0.0 : 1.0, 0.0 };
    cross3(u1, ax, u2);
    double nn = sqrt(u2[0]*u2[0] + u2[1]*u2[1] + u2[2]*u2[2]);
    u2[0] /= nn; u2[1] /= nn; u2[2] /= nn;
  }
  double u3[3], v3[3];
  cross3(u1, u2, u3);
  cross3(v1, v2, v3);
  double Rd[3][3];
  for (int i = 0; i < 3; i++)
    for (int j = 0; j < 3; j++)
      Rd[i][j] = v1[i] * u1[j] + v2[i] * u2[j] + v3[i] * u3[j];
  for (int i = 0; i < 3; i++) {
    double t = cr[i] - (Rd[i][0] * cs[0] + Rd[i][1] * cs[1] + Rd[i][2] * cs[2]);
    tf[i] = (float)t;
    for (int j = 0; j < 3; j++) Rf[i * 3 + j] = (float)Rd[i][j];
  }
}

// ---------------- kernel A: exp + mutual top-3 + w + corr lists + per-patch Procrustes ----
__global__ __launch_bounds__(256) void kA(const float* __restrict__ ref,
                                          const float* __restrict__ src,
                                          const float* __restrict__ score,
                                          float* __restrict__ wout,
                                          Ws* __restrict__ ws) {
  const int b = blockIdx.x;
  const int tid = threadIdx.x;
  __shared__ float se[NM][NN];                 // 16 KB
  __shared__ unsigned long long rowmask[NM], colmask[NN];
  __shared__ int rsel[NM][KSEL];
  __shared__ float red[16][SLOTS];             // 12 KB
  __shared__ double acc[16];
  __shared__ int scount;

  const float* sc = score + (size_t)b * NM * NN;
  for (int i = tid; i < NM * NN; i += 256)
    se[i >> 6][i & 63] = expf(sc[i]);
  if (tid == 0) scount = 0;
  __syncthreads();

  if (tid < NM) {                               // top-3 per row m (over n)
    const int m = tid;
    float v0 = -1e30f, v1 = -1e30f, v2 = -1e30f; int j0 = 0, j1 = 0, j2 = 0;
    for (int n = 0; n < NN; n++) {
      float v = se[m][n];
      if (v > v0) { v2 = v1; j2 = j1; v1 = v0; j1 = j0; v0 = v; j0 = n; }
      else if (v > v1) { v2 = v1; j2 = j1; v1 = v; j1 = n; }
      else if (v > v2) { v2 = v; j2 = n; }
    }
    rsel[m][0] = j0; rsel[m][1] = j1; rsel[m][2] = j2;
    rowmask[m] = (1ull << j0) | (1ull << j1) | (1ull << j2);
  } else if (tid < 128) {                       // top-3 per column n (over m)
    const int n = tid - 64;
    float v0 = -1e30f, v1 = -1e30f, v2 = -1e30f; int j0 = 0, j1 = 0, j2 = 0;
    for (int m = 0; m < NM; m++) {
      float v = se[m][n];
      if (v > v0) { v2 = v1; j2 = j1; v1 = v0; j1 = j0; v0 = v; j0 = m; }
      else if (v > v1) { v2 = v1; j2 = j1; v1 = v; j1 = m; }
      else if (v > v2) { v2 = v; j2 = m; }
    }
    colmask[n] = (1ull << j0) | (1ull << j1) | (1ull << j2);
  }
  __syncthreads();

  // dense w output
  float* wo = wout + (size_t)b * NM * NN;
  for (int i = tid; i < NM * NN; i += 256) {
    int m = i >> 6, n = i & 63;
    float e = se[m][n];
    bool corr = ((rowmask[m] >> n) & 1ull) && ((colmask[n] >> m) & 1ull) && (e > CONF_TH);
    wo[i] = corr ? e : 0.0f;
  }

  // compact slots (m,k) -> n, w ; and per-slot Procrustes partials
  if (tid < SLOTS) {
    int m = tid / 3;
    int k = tid - m * 3;
    int n = rsel[m][k];
    float e = se[m][n];
    bool corr = ((colmask[n] >> m) & 1ull) && (e > CONF_TH);
    float cw = corr ? e : 0.0f;
    ws->corr_n[b * SLOTS + tid] = n;
    ws->corr_w[b * SLOTS + tid] = cw;
    if (corr) atomicAdd(&scount, 1);
    float rx = ref[((size_t)b * NM + m) * 3 + 0];
    float ry = ref[((size_t)b * NM + m) * 3 + 1];
    float rz = ref[((size_t)b * NM + m) * 3 + 2];
    float sx = src[((size_t)b * NN + n) * 3 + 0];
    float sy = src[((size_t)b * NN + n) * 3 + 1];
    float sz = src[((size_t)b * NN + n) * 3 + 2];
    red[0][tid] = cw;
    red[1][tid] = cw * rx;  red[2][tid] = cw * ry;  red[3][tid] = cw * rz;
    red[4][tid] = cw * sx;  red[5][tid] = cw * sy;  red[6][tid] = cw * sz;
    red[7][tid]  = cw * sx * rx; red[8][tid]  = cw * sx * ry; red[9][tid]  = cw * sx * rz;
    red[10][tid] = cw * sy * rx; red[11][tid] = cw * sy * ry; red[12][tid] = cw * sy * rz;
    red[13][tid] = cw * sz * rx; red[14][tid] = cw * sz * ry; red[15][tid] = cw * sz * rz;
  }
  __syncthreads();
  if (tid < 16) {
    double s = 0;
    for (int i = 0; i < SLOTS; i++) s += (double)red[tid][i];
    acc[tid] = s;
  }
  __syncthreads();
  if (tid == 0) {
    float Rf[9], tf[3];
    solve_rigid(acc, Rf, tf);
    for (int i = 0; i < 9; i++) ws->Rb[b * 9 + i] = Rf[i];
    for (int i = 0; i < 3; i++) ws->tb[b * 3 + i] = tf[i];
    ws->ncorr[b] = scount;
    if (b == 0) ws->bestkey = 0;
  }
}

// ---------------- kernel B: verify candidate p over all correspondences -------------------
__global__ __launch_bounds__(256) void kB(const float* __restrict__ ref,
                                          const float* __restrict__ src,
                                          Ws* __restrict__ ws) {
  const int p = blockIdx.x;
  const int tid = threadIdx.x;
  float R[9], T[3];
#pragma unroll
  for (int i = 0; i < 9; i++) R[i] = ws->Rb[p * 9 + i];
#pragma unroll
  for (int i = 0; i < 3; i++) T[i] = ws->tb[p * 3 + i];

  int cnt = 0;
  for (int g = tid; g < TOTSLOTS; g += 256) {
    float w = ws->corr_w[g];
    if (w > 0.0f) {
      int b = g / SLOTS;
      int slot = g - b * SLOTS;
      int m = slot / 3;
      int n = ws->corr_n[g];
      const float* rp = ref + ((size_t)b * NM + m) * 3;
      const float* sp = src + ((size_t)b * NN + n) * 3;
      float sx = sp[0], sy = sp[1], sz = sp[2];
      float rx = rp[0], ry = rp[1], rz = rp[2];
      float mx = R[0] * sx + R[1] * sy + R[2] * sz + T[0];
      float my = R[3] * sx + R[4] * sy + R[5] * sz + T[1];
      float mz = R[6] * sx + R[7] * sy + R[8] * sz + T[2];
      float d2 = (rx * rx + ry * ry + rz * rz) + (mx * mx + my * my + mz * mz)
               - 2.0f * (rx * mx + ry * my + rz * mz);
      cnt += (d2 < RAD2) ? 1 : 0;
    }
  }
  __shared__ int sred[256];
  sred[tid] = cnt;
  __syncthreads();
  for (int s = 128; s > 0; s >>= 1) {
    if (tid < s) sred[tid] += sred[tid + s];
    __syncthreads();
  }
  if (tid == 0) {
    int c = (ws->ncorr[p] >= 3) ? sred[0] : -1;
    int key = ((c + 1) << 8) | (127 - p);   // ties -> smaller p wins (first-index argmax)
    atomicMax(&ws->bestkey, key);
  }
}

// ---------------- kernel C: 5 global Procrustes refinement iterations ---------------------
__global__ __launch_bounds__(256) void kC(const float* __restrict__ ref,
                                          const float* __restrict__ src,
                                          float* __restrict__ outT,
                                          Ws* __restrict__ ws) {
  const int tid = threadIdx.x;
  __shared__ float sR[9], sT[3];
  __shared__ double dacc[16][4];
  if (tid == 0) {
    int p = 127 - (ws->bestkey & 0xFF);
    for (int i = 0; i < 9; i++) sR[i] = ws->Rb[p * 9 + i];
    for (int i = 0; i < 3; i++) sT[i] = ws->tb[p * 3 + i];
  }
  __syncthreads();

  for (int iter = 0; iter < 5; iter++) {
    float R0 = sR[0], R1 = sR[1], R2 = sR[2];
    float R3 = sR[3], R4 = sR[4], R5 = sR[5];
    float R6 = sR[6], R7 = sR[7], R8 = sR[8];
    float T0 = sT[0], T1 = sT[1], T2 = sT[2];
    double la[16];
#pragma unroll
    for (int q = 0; q < 16; q++) la[q] = 0.0;

    for (int g = tid; g < TOTSLOTS; g += 256) {
      float w = ws->corr_w[g];
      if (w <= 0.0f) continue;
      int b = g / SLOTS;
      int slot = g - b * SLOTS;
      int m = slot / 3;
      int n = ws->corr_n[g];
      const float* rp = ref + ((size_t)b * NM + m) * 3;
      const float* sp = src + ((size_t)b * NN + n) * 3;
      float sx = sp[0], sy = sp[1], sz = sp[2];
      float rx = rp[0], ry = rp[1], rz = rp[2];
      float mx = R0 * sx + R1 * sy + R2 * sz + T0;
      float my = R3 * sx + R4 * sy + R5 * sz + T1;
      float mz = R6 * sx + R7 * sy + R8 * sz + T2;
      float d2 = (rx * rx + ry * ry + rz * rz) + (mx * mx + my * my + mz * mz)
               - 2.0f * (rx * mx + ry * my + rz * mz);
      if (d2 < RAD2) {
        double w_ = (double)w;
        la[0] += w_;
        la[1] += w_ * rx;  la[2] += w_ * ry;  la[3] += w_ * rz;
        la[4] += w_ * sx;  la[5] += w_ * sy;  la[6] += w_ * sz;
        la[7]  += w_ * sx * rx; la[8]  += w_ * sx * ry; la[9]  += w_ * sx * rz;
        la[10] += w_ * sy * rx; la[11] += w_ * sy * ry; la[12] += w_ * sy * rz;
        la[13] += w_ * sz * rx; la[14] += w_ * sz * ry; la[15] += w_ * sz * rz;
      }
    }
#pragma unroll
    for (int q = 0; q < 16; q++) {
      double v = la[q];
      for (int off = 32; off > 0; off >>= 1) v += __shfl_down(v, off);
      if ((tid & 63) == 0) dacc[q][tid >> 6] = v;
    }
    __syncthreads();
    if (tid == 0) {
      double acc[16];
      for (int q = 0; q < 16; q++) acc[q] = dacc[q][0] + dacc[q][1] + dacc[q][2] + dacc[q][3];
      float Rf[9], tf[3];
      solve_rigid(acc, Rf, tf);
      for (int i = 0; i < 9; i++) sR[i] = Rf[i];
      for (int i = 0; i < 3; i++) sT[i] = tf[i];
    }
    __syncthreads();
  }

  if (tid == 0) {
    outT[0] = sR[0]; outT[1] = sR[1]; outT[2]  = sR[2]; outT[3]  = sT[0];
    outT[4] = sR[3]; outT[5] = sR[4]; outT[6]  = sR[5]; outT[7]  = sT[1];
    outT[8] = sR[6]; outT[9] = sR[7]; outT[10] = sR[8]; outT[11] = sT[2];
    outT[12] = 0.0f; outT[13] = 0.0f; outT[14] = 0.0f; outT[15] = 1.0f;
  }
}

extern "C" void kernel_launch(void* const* d_in, const int* in_sizes, int n_in,
                              void* d_out, int out_size, void* d_ws, size_t ws_size,
                              hipStream_t stream) {
  const float* ref   = (const float*)d_in[0];
  const float* src   = (const float*)d_in[1];
  const float* score = (const float*)d_in[2];
  float* w    = (float*)d_out;
  float* outT = (float*)d_out + (size_t)NB * NM * NN;
  Ws* ws = (Ws*)d_ws;

  kA<<<NB, 256, 0, stream>>>(ref, src, score, w, ws);
  kB<<<NB, 256, 0, stream>>>(ref, src, ws);
  kC<<<1, 256, 0, stream>>>(ref, src, outT, ws);
}

// Round 7
// 231.388 us; speedup vs baseline: 1.9964x; 1.9964x over previous
//
#include <hip/hip_runtime.h>
#include <math.h>

#define NB 128
#define NM 64
#define NN 64
#define KSEL 3
#define SLOTS (NM * KSEL)          // 192
#define TOTSLOTS (NB * SLOTS)      // 24576
#define CONF_TH 0.05f
#define RAD2 0.01f                 // ACCEPTANCE_RADIUS^2
#define EPSV 1e-5

// pack[g] = {sx, sy, sz, w} — src point resolved at kA time (kills the data-
// dependent gather in kB/kC). ref is re-read by m = slot/3 (deterministic index,
// L1-resident 98 KB input). Total ws ≈ 400 KB.
struct Ws {
  float4 pack[TOTSLOTS];
  float Rb[NB * 9];
  float tb[NB * 3];
  int   ncorr[NB];
  int   bestkey;
};

__device__ __forceinline__ void mat3vec(const double H[3][3], const double v[3], double o[3]) {
  o[0] = H[0][0] * v[0] + H[0][1] * v[1] + H[0][2] * v[2];
  o[1] = H[1][0] * v[0] + H[1][1] * v[1] + H[1][2] * v[2];
  o[2] = H[2][0] * v[0] + H[2][1] * v[1] + H[2][2] * v[2];
}

__device__ __forceinline__ void cross3(const double a[3], const double b[3], double o[3]) {
  o[0] = a[1] * b[2] - a[2] * b[1];
  o[1] = a[2] * b[0] - a[0] * b[2];
  o[2] = a[0] * b[1] - a[1] * b[0];
}

// acc[0]=S, acc[1..3]=Sum(w*ref), acc[4..6]=Sum(w*src), acc[7+c*3+d]=Sum(w*src_c*ref_d)
// Reproduces: wn = w/(S+eps); H = Sum wn (src-cs)(ref-cr)^T; H=USV^T; R=V diag(1,1,det) U^T
__device__ void solve_rigid(const double* acc, float* Rf, float* tf) {
  double denom = acc[0] + EPSV;
  double cr[3], cs[3];
  for (int i = 0; i < 3; i++) { cr[i] = acc[1 + i] / denom; cs[i] = acc[4 + i] / denom; }
  double sig = acc[0] / denom;
  double H[3][3];
  for (int c = 0; c < 3; c++)
    for (int d = 0; d < 3; d++)
      H[c][d] = acc[7 + c * 3 + d] / denom - (2.0 - sig) * cs[c] * cr[d];

  // A = H^T H (symmetric PSD, in ref-space)
  double A[3][3], V[3][3] = {{1,0,0},{0,1,0},{0,0,1}};
  for (int i = 0; i < 3; i++)
    for (int j = 0; j < 3; j++) {
      double s = 0;
      for (int k = 0; k < 3; k++) s += H[k][i] * H[k][j];
      A[i][j] = s;
    }
  // Cyclic Jacobi; relative early-skip makes converged sweeps ~free.
  for (int sweep = 0; sweep < 15; sweep++) {
    for (int p = 0; p < 3; p++) {
      for (int q = p + 1; q < 3; q++) {
        double apq = A[p][q];
        if (fabs(apq) <= 1e-14 * (fabs(A[p][p]) + fabs(A[q][q]))) continue;
        double tau = (A[q][q] - A[p][p]) / (2.0 * apq);
        double tt = (tau >= 0.0) ? 1.0 / (tau + sqrt(1.0 + tau * tau))
                                 : 1.0 / (tau - sqrt(1.0 + tau * tau));
        double c = 1.0 / sqrt(1.0 + tt * tt), s = tt * c;
        for (int k = 0; k < 3; k++) {      // A <- A*J
          double akp = A[k][p], akq = A[k][q];
          A[k][p] = c * akp - s * akq;
          A[k][q] = s * akp + c * akq;
        }
        for (int k = 0; k < 3; k++) {      // A <- J^T*A
          double apk = A[p][k], aqk = A[q][k];
          A[p][k] = c * apk - s * aqk;
          A[q][k] = s * apk + c * aqk;
        }
        for (int k = 0; k < 3; k++) {      // V <- V*J
          double vkp = V[k][p], vkq = V[k][q];
          V[k][p] = c * vkp - s * vkq;
          V[k][q] = s * vkp + c * vkq;
        }
      }
    }
  }
  double lam[3] = {A[0][0], A[1][1], A[2][2]};
  int i0 = 0, i1 = 1, i2 = 2, tmp;
  if (lam[i0] < lam[i1]) { tmp = i0; i0 = i1; i1 = tmp; }
  if (lam[i0] < lam[i2]) { tmp = i0; i0 = i2; i2 = tmp; }
  if (lam[i1] < lam[i2]) { tmp = i1; i1 = i2; i2 = tmp; }

  double v1[3] = {V[0][i0], V[1][i0], V[2][i0]};
  double v2[3] = {V[0][i1], V[1][i1], V[2][i1]};
  double u1[3], u2[3];
  mat3vec(H, v1, u1);
  double n1 = sqrt(u1[0]*u1[0] + u1[1]*u1[1] + u1[2]*u1[2]);
  if (n1 > 1e-30) { u1[0] /= n1; u1[1] /= n1; u1[2] /= n1; }
  else { u1[0] = 1; u1[1] = 0; u1[2] = 0; }
  mat3vec(H, v2, u2);
  double d12 = u1[0]*u2[0] + u1[1]*u2[1] + u1[2]*u2[2];
  u2[0] -= d12 * u1[0]; u2[1] -= d12 * u1[1]; u2[2] -= d12 * u1[2];
  double n2 = sqrt(u2[0]*u2[0] + u2[1]*u2[1] + u2[2]*u2[2]);
  if (n2 > 1e-30) { u2[0] /= n2; u2[1] /= n2; u2[2] /= n2; }
  else {
    double ax[3] = { (fabs(u1[0]) < 0.9) ? 1.0 : 0.0, (fabs(u1[0]) < 0.9) ? 0.0 : 1.0, 0.0 };
    cross3(u1, ax, u2);
    double nn = sqrt(u2[0]*u2[0] + u2[1]*u2[1] + u2[2]*u2[2]);
    u2[0] /= nn; u2[1] /= nn; u2[2] /= nn;
  }
  double u3[3], v3[3];
  cross3(u1, u2, u3);
  cross3(v1, v2, v3);
  double Rd[3][3];
  for (int i = 0; i < 3; i++)
    for (int j = 0; j < 3; j++)
      Rd[i][j] = v1[i] * u1[j] + v2[i] * u2[j] + v3[i] * u3[j];
  for (int i = 0; i < 3; i++) {
    double t = cr[i] - (Rd[i][0] * cs[0] + Rd[i][1] * cs[1] + Rd[i][2] * cs[2]);
    tf[i] = (float)t;
    for (int j = 0; j < 3; j++) Rf[i * 3 + j] = (float)Rd[i][j];
  }
}

// ---------------- kernel A: exp + mutual top-3 + w + packed corr + per-patch Procrustes ---
__global__ __launch_bounds__(256) void kA(const float* __restrict__ ref,
                                          const float* __restrict__ src,
                                          const float* __restrict__ score,
                                          float* __restrict__ wout,
                                          Ws* __restrict__ ws) {
  const int b = blockIdx.x;
  const int tid = threadIdx.x;
  __shared__ float se[NM][NN + 1];             // +1 pad: row scan (256B stride) conflict-free
  __shared__ unsigned long long rowmask[NM], colmask[NN];
  __shared__ int rsel[NM][KSEL];
  __shared__ float red[16][SLOTS + 1];         // +1 pad: 16-lane column reduce conflict-free
  __shared__ double acc[16];
  __shared__ int scount;

  const float* sc = score + (size_t)b * NM * NN;
  for (int i = tid; i < NM * NN; i += 256)
    se[i >> 6][i & 63] = expf(sc[i]);
  if (tid == 0) scount = 0;
  __syncthreads();

  if (tid < NM) {                               // top-3 per row m (over n)
    const int m = tid;
    float v0 = -1e30f, v1 = -1e30f, v2 = -1e30f; int j0 = 0, j1 = 0, j2 = 0;
    for (int n = 0; n < NN; n++) {
      float v = se[m][n];
      if (v > v0) { v2 = v1; j2 = j1; v1 = v0; j1 = j0; v0 = v; j0 = n; }
      else if (v > v1) { v2 = v1; j2 = j1; v1 = v; j1 = n; }
      else if (v > v2) { v2 = v; j2 = n; }
    }
    rsel[m][0] = j0; rsel[m][1] = j1; rsel[m][2] = j2;
    rowmask[m] = (1ull << j0) | (1ull << j1) | (1ull << j2);
  } else if (tid < 128) {                       // top-3 per column n (over m)
    const int n = tid - 64;
    float v0 = -1e30f, v1 = -1e30f, v2 = -1e30f; int j0 = 0, j1 = 0, j2 = 0;
    for (int m = 0; m < NM; m++) {
      float v = se[m][n];
      if (v > v0) { v2 = v1; j2 = j1; v1 = v0; j1 = j0; v0 = v; j0 = m; }
      else if (v > v1) { v2 = v1; j2 = j1; v1 = v; j1 = m; }
      else if (v > v2) { v2 = v; j2 = m; }
    }
    colmask[n] = (1ull << j0) | (1ull << j1) | (1ull << j2);
  }
  __syncthreads();

  // dense w output
  float* wo = wout + (size_t)b * NM * NN;
  for (int i = tid; i < NM * NN; i += 256) {
    int m = i >> 6, n = i & 63;
    float e = se[m][n];
    bool corr = ((rowmask[m] >> n) & 1ull) && ((colmask[n] >> m) & 1ull) && (e > CONF_TH);
    wo[i] = corr ? e : 0.0f;
  }

  // packed slots (m,k) -> {src point, w}; and per-slot Procrustes partials
  if (tid < SLOTS) {
    int m = tid / 3;
    int k = tid - m * 3;
    int n = rsel[m][k];
    float e = se[m][n];
    bool corr = ((colmask[n] >> m) & 1ull) && (e > CONF_TH);
    float cw = corr ? e : 0.0f;
    float rx = ref[((size_t)b * NM + m) * 3 + 0];
    float ry = ref[((size_t)b * NM + m) * 3 + 1];
    float rz = ref[((size_t)b * NM + m) * 3 + 2];
    float sx = src[((size_t)b * NN + n) * 3 + 0];
    float sy = src[((size_t)b * NN + n) * 3 + 1];
    float sz = src[((size_t)b * NN + n) * 3 + 2];
    ws->pack[b * SLOTS + tid] = make_float4(sx, sy, sz, cw);
    if (corr) atomicAdd(&scount, 1);
    red[0][tid] = cw;
    red[1][tid] = cw * rx;  red[2][tid] = cw * ry;  red[3][tid] = cw * rz;
    red[4][tid] = cw * sx;  red[5][tid] = cw * sy;  red[6][tid] = cw * sz;
    red[7][tid]  = cw * sx * rx; red[8][tid]  = cw * sx * ry; red[9][tid]  = cw * sx * rz;
    red[10][tid] = cw * sy * rx; red[11][tid] = cw * sy * ry; red[12][tid] = cw * sy * rz;
    red[13][tid] = cw * sz * rx; red[14][tid] = cw * sz * ry; red[15][tid] = cw * sz * rz;
  }
  __syncthreads();
  if (tid < 16) {
    double s = 0;
    for (int i = 0; i < SLOTS; i++) s += (double)red[tid][i];
    acc[tid] = s;
  }
  __syncthreads();
  if (tid == 0) {
    float Rf[9], tf[3];
    solve_rigid(acc, Rf, tf);
    for (int i = 0; i < 9; i++) ws->Rb[b * 9 + i] = Rf[i];
    for (int i = 0; i < 3; i++) ws->tb[b * 3 + i] = tf[i];
    ws->ncorr[b] = scount;
    if (b == 0) ws->bestkey = 0;
  }
}

// ---------------- kernel B: verify candidate p over all correspondences (packed stream) ---
__global__ __launch_bounds__(256) void kB(const float* __restrict__ ref,
                                          Ws* __restrict__ ws) {
  const int p = blockIdx.x;
  const int tid = threadIdx.x;
  float R[9], T[3];
#pragma unroll
  for (int i = 0; i < 9; i++) R[i] = ws->Rb[p * 9 + i];
#pragma unroll
  for (int i = 0; i < 3; i++) T[i] = ws->tb[p * 3 + i];

  int cnt = 0;
  for (int g = tid; g < TOTSLOTS; g += 256) {
    float4 P = ws->pack[g];
    int b = g / SLOTS;
    int m = (g - b * SLOTS) / 3;
    const float* rp = ref + ((size_t)b * NM + m) * 3;
    float rx = rp[0], ry = rp[1], rz = rp[2];
    float sx = P.x, sy = P.y, sz = P.z;
    float mx = R[0] * sx + R[1] * sy + R[2] * sz + T[0];
    float my = R[3] * sx + R[4] * sy + R[5] * sz + T[1];
    float mz = R[6] * sx + R[7] * sy + R[8] * sz + T[2];
    float d2 = (rx * rx + ry * ry + rz * rz) + (mx * mx + my * my + mz * mz)
             - 2.0f * (rx * mx + ry * my + rz * mz);
    cnt += (P.w > 0.0f && d2 < RAD2) ? 1 : 0;
  }
  __shared__ int sred[256];
  sred[tid] = cnt;
  __syncthreads();
  for (int s = 128; s > 0; s >>= 1) {
    if (tid < s) sred[tid] += sred[tid + s];
    __syncthreads();
  }
  if (tid == 0) {
    int c = (ws->ncorr[p] >= 3) ? sred[0] : -1;
    int key = ((c + 1) << 8) | (127 - p);   // ties -> smaller p wins (first-index argmax)
    atomicMax(&ws->bestkey, key);
  }
}

// ---------------- kernel C: 5 global Procrustes refinement iterations (1024 thr, 16 waves)
__global__ __launch_bounds__(1024) void kC(const float* __restrict__ ref,
                                           float* __restrict__ outT,
                                           Ws* __restrict__ ws) {
  const int tid = threadIdx.x;
  const int wid = tid >> 6, lane = tid & 63;
  __shared__ float sR[9], sT[3];
  __shared__ double wsum[16][16];   // [quantity][wave]
  __shared__ double acc[16];
  if (tid == 0) {
    int p = 127 - (ws->bestkey & 0xFF);
    for (int i = 0; i < 9; i++) sR[i] = ws->Rb[p * 9 + i];
    for (int i = 0; i < 3; i++) sT[i] = ws->tb[p * 3 + i];
  }
  __syncthreads();

  for (int iter = 0; iter < 5; iter++) {
    float R0 = sR[0], R1 = sR[1], R2 = sR[2];
    float R3 = sR[3], R4 = sR[4], R5 = sR[5];
    float R6 = sR[6], R7 = sR[7], R8 = sR[8];
    float T0 = sT[0], T1 = sT[1], T2 = sT[2];
    double la[16];
#pragma unroll
    for (int q = 0; q < 16; q++) la[q] = 0.0;

    for (int g = tid; g < TOTSLOTS; g += 1024) {      // 24 coalesced iters/thread
      float4 P = ws->pack[g];
      int b = g / SLOTS;
      int m = (g - b * SLOTS) / 3;
      const float* rp = ref + ((size_t)b * NM + m) * 3;
      float rx = rp[0], ry = rp[1], rz = rp[2];
      float sx = P.x, sy = P.y, sz = P.z;
      float mx = R0 * sx + R1 * sy + R2 * sz + T0;
      float my = R3 * sx + R4 * sy + R5 * sz + T1;
      float mz = R6 * sx + R7 * sy + R8 * sz + T2;
      float d2 = (rx * rx + ry * ry + rz * rz) + (mx * mx + my * my + mz * mz)
               - 2.0f * (rx * mx + ry * my + rz * mz);
      float w_ = (d2 < RAD2) ? P.w : 0.0f;            // branchless gate (w=0 pads drop out)
      la[0]  += (double)w_;
      la[1]  += (double)(w_ * rx); la[2]  += (double)(w_ * ry); la[3]  += (double)(w_ * rz);
      la[4]  += (double)(w_ * sx); la[5]  += (double)(w_ * sy); la[6]  += (double)(w_ * sz);
      la[7]  += (double)(w_ * sx * rx); la[8]  += (double)(w_ * sx * ry); la[9]  += (double)(w_ * sx * rz);
      la[10] += (double)(w_ * sy * rx); la[11] += (double)(w_ * sy * ry); la[12] += (double)(w_ * sy * rz);
      la[13] += (double)(w_ * sz * rx); la[14] += (double)(w_ * sz * ry); la[15] += (double)(w_ * sz * rz);
    }
#pragma unroll
    for (int q = 0; q < 16; q++) {
      double v = la[q];
      for (int off = 32; off > 0; off >>= 1) v += __shfl_down(v, off);
      if (lane == 0) wsum[q][wid] = v;
    }
    __syncthreads();
    if (tid < 16) {
      double s = 0;
      for (int k = 0; k < 16; k++) s += wsum[tid][k];
      acc[tid] = s;
    }
    __syncthreads();
    if (tid == 0) {
      float Rf[9], tf[3];
      solve_rigid(acc, Rf, tf);
      for (int i = 0; i < 9; i++) sR[i] = Rf[i];
      for (int i = 0; i < 3; i++) sT[i] = tf[i];
    }
    __syncthreads();
  }

  if (tid == 0) {
    outT[0] = sR[0]; outT[1] = sR[1]; outT[2]  = sR[2]; outT[3]  = sT[0];
    outT[4] = sR[3]; outT[5] = sR[4]; outT[6]  = sR[5]; outT[7]  = sT[1];
    outT[8] = sR[6]; outT[9] = sR[7]; outT[10] = sR[8]; outT[11] = sT[2];
    outT[12] = 0.0f; outT[13] = 0.0f; outT[14] = 0.0f; outT[15] = 1.0f;
  }
}

extern "C" void kernel_launch(void* const* d_in, const int* in_sizes, int n_in,
                              void* d_out, int out_size, void* d_ws, size_t ws_size,
                              hipStream_t stream) {
  const float* ref   = (const float*)d_in[0];
  const float* src   = (const float*)d_in[1];
  const float* score = (const float*)d_in[2];
  float* w    = (float*)d_out;
  float* outT = (float*)d_out + (size_t)NB * NM * NN;
  Ws* ws = (Ws*)d_ws;

  kA<<<NB, 256, 0, stream>>>(ref, src, score, w, ws);
  kB<<<NB, 256, 0, stream>>>(ref, ws);
  kC<<<1, 1024, 0, stream>>>(ref, outT, ws);
}

// Round 9
// 203.395 us; speedup vs baseline: 2.2711x; 1.1376x over previous
//
#include <hip/hip_runtime.h>
#include <math.h>

#define NB 128
#define NM 64
#define NN 64
#define KSEL 3
#define SLOTS (NM * KSEL)          // 192
#define TOTSLOTS (NB * SLOTS)      // 24576
#define CONF_TH 0.05f
#define RAD2 0.01f                 // ACCEPTANCE_RADIUS^2
#define EPSV 1e-5

// Slot = {src.xyz, w} + {ref.xyz, pad} resolved at kA time. One 32B line per
// correspondence: kB/kC read 2 coalesced dwordx4, zero index math, no gather.
struct Slot {
  float4 s;   // sx, sy, sz, w
  float4 r;   // rx, ry, rz, 0
};

struct Ws {
  Slot  pack[TOTSLOTS];   // 768 KB
  float Rb[NB * 9];
  float tb[NB * 3];
  int   ncorr[NB];
  int   bestkey;
};

__device__ __forceinline__ void mat3vec(const double H[3][3], const double v[3], double o[3]) {
  o[0] = H[0][0] * v[0] + H[0][1] * v[1] + H[0][2] * v[2];
  o[1] = H[1][0] * v[0] + H[1][1] * v[1] + H[1][2] * v[2];
  o[2] = H[2][0] * v[0] + H[2][1] * v[1] + H[2][2] * v[2];
}

__device__ __forceinline__ void cross3(const double a[3], const double b[3], double o[3]) {
  o[0] = a[1] * b[2] - a[2] * b[1];
  o[1] = a[2] * b[0] - a[0] * b[2];
  o[2] = a[0] * b[1] - a[1] * b[0];
}

// acc[0]=S, acc[1..3]=Sum(w*ref), acc[4..6]=Sum(w*src), acc[7+c*3+d]=Sum(w*src_c*ref_d)
// Reproduces: wn = w/(S+eps); H = Sum wn (src-cs)(ref-cr)^T; H=USV^T; R=V diag(1,1,det) U^T
__device__ void solve_rigid(const double* acc, float* Rf, float* tf) {
  double denom = acc[0] + EPSV;
  double cr[3], cs[3];
  for (int i = 0; i < 3; i++) { cr[i] = acc[1 + i] / denom; cs[i] = acc[4 + i] / denom; }
  double sig = acc[0] / denom;
  double H[3][3];
  for (int c = 0; c < 3; c++)
    for (int d = 0; d < 3; d++)
      H[c][d] = acc[7 + c * 3 + d] / denom - (2.0 - sig) * cs[c] * cr[d];

  // A = H^T H (symmetric PSD, in ref-space)
  double A[3][3], V[3][3] = {{1,0,0},{0,1,0},{0,0,1}};
  for (int i = 0; i < 3; i++)
    for (int j = 0; j < 3; j++) {
      double s = 0;
      for (int k = 0; k < 3; k++) s += H[k][i] * H[k][j];
      A[i][j] = s;
    }
  // Cyclic Jacobi; relative early-skip makes converged sweeps ~free.
  for (int sweep = 0; sweep < 15; sweep++) {
    for (int p = 0; p < 3; p++) {
      for (int q = p + 1; q < 3; q++) {
        double apq = A[p][q];
        if (fabs(apq) <= 1e-14 * (fabs(A[p][p]) + fabs(A[q][q]))) continue;
        double tau = (A[q][q] - A[p][p]) / (2.0 * apq);
        double tt = (tau >= 0.0) ? 1.0 / (tau + sqrt(1.0 + tau * tau))
                                 : 1.0 / (tau - sqrt(1.0 + tau * tau));
        double c = 1.0 / sqrt(1.0 + tt * tt), s = tt * c;
        for (int k = 0; k < 3; k++) {      // A <- A*J
          double akp = A[k][p], akq = A[k][q];
          A[k][p] = c * akp - s * akq;
          A[k][q] = s * akp + c * akq;
        }
        for (int k = 0; k < 3; k++) {      // A <- J^T*A
          double apk = A[p][k], aqk = A[q][k];
          A[p][k] = c * apk - s * aqk;
          A[q][k] = s * apk + c * aqk;
        }
        for (int k = 0; k < 3; k++) {      // V <- V*J
          double vkp = V[k][p], vkq = V[k][q];
          V[k][p] = c * vkp - s * vkq;
          V[k][q] = s * vkp + c * vkq;
        }
      }
    }
  }
  double lam[3] = {A[0][0], A[1][1], A[2][2]};
  int i0 = 0, i1 = 1, i2 = 2, tmp;
  if (lam[i0] < lam[i1]) { tmp = i0; i0 = i1; i1 = tmp; }
  if (lam[i0] < lam[i2]) { tmp = i0; i0 = i2; i2 = tmp; }
  if (lam[i1] < lam[i2]) { tmp = i1; i1 = i2; i2 = tmp; }

  double v1[3] = {V[0][i0], V[1][i0], V[2][i0]};
  double v2[3] = {V[0][i1], V[1][i1], V[2][i1]};
  double u1[3], u2[3];
  mat3vec(H, v1, u1);
  double n1 = sqrt(u1[0]*u1[0] + u1[1]*u1[1] + u1[2]*u1[2]);
  if (n1 > 1e-30) { u1[0] /= n1; u1[1] /= n1; u1[2] /= n1; }
  else { u1[0] = 1; u1[1] = 0; u1[2] = 0; }
  mat3vec(H, v2, u2);
  double d12 = u1[0]*u2[0] + u1[1]*u2[1] + u1[2]*u2[2];
  u2[0] -= d12 * u1[0]; u2[1] -= d12 * u1[1]; u2[2] -= d12 * u1[2];
  double n2 = sqrt(u2[0]*u2[0] + u2[1]*u2[1] + u2[2]*u2[2]);
  if (n2 > 1e-30) { u2[0] /= n2; u2[1] /= n2; u2[2] /= n2; }
  else {
    double ax[3] = { (fabs(u1[0]) < 0.9) ? 1.0 : 0.0, (fabs(u1[0]) < 0.9) ? 0.0 : 1.0, 0.0 };
    cross3(u1, ax, u2);
    double nn = sqrt(u2[0]*u2[0] + u2[1]*u2[1] + u2[2]*u2[2]);
    u2[0] /= nn; u2[1] /= nn; u2[2] /= nn;
  }
  double u3[3], v3[3];
  cross3(u1, u2, u3);
  cross3(v1, v2, v3);
  double Rd[3][3];
  for (int i = 0; i < 3; i++)
    for (int j = 0; j < 3; j++)
      Rd[i][j] = v1[i] * u1[j] + v2[i] * u2[j] + v3[i] * u3[j];
  for (int i = 0; i < 3; i++) {
    double t = cr[i] - (Rd[i][0] * cs[0] + Rd[i][1] * cs[1] + Rd[i][2] * cs[2]);
    tf[i] = (float)t;
    for (int j = 0; j < 3; j++) Rf[i * 3 + j] = (float)Rd[i][j];
  }
}

// ---------------- kernel A: exp + mutual top-3 + w + packed corr + per-patch Procrustes ---
__global__ __launch_bounds__(256) void kA(const float* __restrict__ ref,
                                          const float* __restrict__ src,
                                          const float* __restrict__ score,
                                          float* __restrict__ wout,
                                          Ws* __restrict__ ws) {
  const int b = blockIdx.x;
  const int tid = threadIdx.x;
  __shared__ float se[NM][NN + 1];             // +1 pad: row scan (256B stride) conflict-free
  __shared__ unsigned long long rowmask[NM], colmask[NN];
  __shared__ int rsel[NM][KSEL];
  __shared__ float red[16][SLOTS + 1];         // +1 pad: 16-lane column reduce conflict-free
  __shared__ double acc[16];
  __shared__ int scount;

  const float* sc = score + (size_t)b * NM * NN;
  for (int i = tid; i < NM * NN; i += 256)
    se[i >> 6][i & 63] = expf(sc[i]);
  if (tid == 0) scount = 0;
  __syncthreads();

  if (tid < NM) {                               // top-3 per row m (over n)
    const int m = tid;
    float v0 = -1e30f, v1 = -1e30f, v2 = -1e30f; int j0 = 0, j1 = 0, j2 = 0;
    for (int n = 0; n < NN; n++) {
      float v = se[m][n];
      if (v > v0) { v2 = v1; j2 = j1; v1 = v0; j1 = j0; v0 = v; j0 = n; }
      else if (v > v1) { v2 = v1; j2 = j1; v1 = v; j1 = n; }
      else if (v > v2) { v2 = v; j2 = n; }
    }
    rsel[m][0] = j0; rsel[m][1] = j1; rsel[m][2] = j2;
    rowmask[m] = (1ull << j0) | (1ull << j1) | (1ull << j2);
  } else if (tid < 128) {                       // top-3 per column n (over m)
    const int n = tid - 64;
    float v0 = -1e30f, v1 = -1e30f, v2 = -1e30f; int j0 = 0, j1 = 0, j2 = 0;
    for (int m = 0; m < NM; m++) {
      float v = se[m][n];
      if (v > v0) { v2 = v1; j2 = j1; v1 = v0; j1 = j0; v0 = v; j0 = m; }
      else if (v > v1) { v2 = v1; j2 = j1; v1 = v; j1 = m; }
      else if (v > v2) { v2 = v; j2 = m; }
    }
    colmask[n] = (1ull << j0) | (1ull << j1) | (1ull << j2);
  }
  __syncthreads();

  // dense w output
  float* wo = wout + (size_t)b * NM * NN;
  for (int i = tid; i < NM * NN; i += 256) {
    int m = i >> 6, n = i & 63;
    float e = se[m][n];
    bool corr = ((rowmask[m] >> n) & 1ull) && ((colmask[n] >> m) & 1ull) && (e > CONF_TH);
    wo[i] = corr ? e : 0.0f;
  }

  // packed slots (m,k) -> {src,w}+{ref}; and per-slot Procrustes partials
  if (tid < SLOTS) {
    int m = tid / 3;
    int k = tid - m * 3;
    int n = rsel[m][k];
    float e = se[m][n];
    bool corr = ((colmask[n] >> m) & 1ull) && (e > CONF_TH);
    float cw = corr ? e : 0.0f;
    float rx = ref[((size_t)b * NM + m) * 3 + 0];
    float ry = ref[((size_t)b * NM + m) * 3 + 1];
    float rz = ref[((size_t)b * NM + m) * 3 + 2];
    float sx = src[((size_t)b * NN + n) * 3 + 0];
    float sy = src[((size_t)b * NN + n) * 3 + 1];
    float sz = src[((size_t)b * NN + n) * 3 + 2];
    ws->pack[b * SLOTS + tid].s = make_float4(sx, sy, sz, cw);
    ws->pack[b * SLOTS + tid].r = make_float4(rx, ry, rz, 0.0f);
    if (corr) atomicAdd(&scount, 1);
    red[0][tid] = cw;
    red[1][tid] = cw * rx;  red[2][tid] = cw * ry;  red[3][tid] = cw * rz;
    red[4][tid] = cw * sx;  red[5][tid] = cw * sy;  red[6][tid] = cw * sz;
    red[7][tid]  = cw * sx * rx; red[8][tid]  = cw * sx * ry; red[9][tid]  = cw * sx * rz;
    red[10][tid] = cw * sy * rx; red[11][tid] = cw * sy * ry; red[12][tid] = cw * sy * rz;
    red[13][tid] = cw * sz * rx; red[14][tid] = cw * sz * ry; red[15][tid] = cw * sz * rz;
  }
  __syncthreads();
  if (tid < 16) {
    double s = 0;
    for (int i = 0; i < SLOTS; i++) s += (double)red[tid][i];
    acc[tid] = s;
  }
  __syncthreads();
  if (tid == 0) {
    float Rf[9], tf[3];
    solve_rigid(acc, Rf, tf);
    for (int i = 0; i < 9; i++) ws->Rb[b * 9 + i] = Rf[i];
    for (int i = 0; i < 3; i++) ws->tb[b * 3 + i] = tf[i];
    ws->ncorr[b] = scount;
    if (b == 0) ws->bestkey = 0;
  }
}

// ---------------- kernel B: verify candidate p over all correspondences (packed stream) ---
__global__ __launch_bounds__(256) void kB(Ws* __restrict__ ws) {
  const int p = blockIdx.x;
  const int tid = threadIdx.x;
  float R[9], T[3];
#pragma unroll
  for (int i = 0; i < 9; i++) R[i] = ws->Rb[p * 9 + i];
#pragma unroll
  for (int i = 0; i < 3; i++) T[i] = ws->tb[p * 3 + i];

  int cnt = 0;
  for (int g = tid; g < TOTSLOTS; g += 256) {
    float4 S = ws->pack[g].s;
    float4 Rv = ws->pack[g].r;
    float sx = S.x, sy = S.y, sz = S.z;
    float rx = Rv.x, ry = Rv.y, rz = Rv.z;
    float mx = R[0] * sx + R[1] * sy + R[2] * sz + T[0];
    float my = R[3] * sx + R[4] * sy + R[5] * sz + T[1];
    float mz = R[6] * sx + R[7] * sy + R[8] * sz + T[2];
    float d2 = (rx * rx + ry * ry + rz * rz) + (mx * mx + my * my + mz * mz)
             - 2.0f * (rx * mx + ry * my + rz * mz);
    cnt += (S.w > 0.0f && d2 < RAD2) ? 1 : 0;
  }
  __shared__ int sred[256];
  sred[tid] = cnt;
  __syncthreads();
  for (int s = 128; s > 0; s >>= 1) {
    if (tid < s) sred[tid] += sred[tid + s];
    __syncthreads();
  }
  if (tid == 0) {
    int c = (ws->ncorr[p] >= 3) ? sred[0] : -1;
    int key = ((c + 1) << 8) | (127 - p);   // ties -> smaller p wins (first-index argmax)
    atomicMax(&ws->bestkey, key);
  }
}

// ---------------- kernel C: 5 global Procrustes refinement iterations (1024 thr, 16 waves)
// f32 FMA per-thread partials + f32 wave shfl-tree, widened to f64 at wave partials.
// (Reference computes these einsums in f32; our error lands at its noise floor.)
__global__ __launch_bounds__(1024) void kC(float* __restrict__ outT,
                                           Ws* __restrict__ ws) {
  const int tid = threadIdx.x;
  const int wid = tid >> 6, lane = tid & 63;
  __shared__ float sR[9], sT[3];
  __shared__ double wsum[16][16];   // [quantity][wave]
  __shared__ double acc[16];
  if (tid == 0) {
    int p = 127 - (ws->bestkey & 0xFF);
    for (int i = 0; i < 9; i++) sR[i] = ws->Rb[p * 9 + i];
    for (int i = 0; i < 3; i++) sT[i] = ws->tb[p * 3 + i];
  }
  __syncthreads();

  for (int iter = 0; iter < 5; iter++) {
    float R0 = sR[0], R1 = sR[1], R2 = sR[2];
    float R3 = sR[3], R4 = sR[4], R5 = sR[5];
    float R6 = sR[6], R7 = sR[7], R8 = sR[8];
    float T0 = sT[0], T1 = sT[1], T2 = sT[2];
    float la[16];
#pragma unroll
    for (int q = 0; q < 16; q++) la[q] = 0.0f;

#pragma unroll 4
    for (int g = tid; g < TOTSLOTS; g += 1024) {      // 24 coalesced iters/thread
      float4 S = ws->pack[g].s;
      float4 Rv = ws->pack[g].r;
      float sx = S.x, sy = S.y, sz = S.z;
      float rx = Rv.x, ry = Rv.y, rz = Rv.z;
      float mx = R0 * sx + R1 * sy + R2 * sz + T0;
      float my = R3 * sx + R4 * sy + R5 * sz + T1;
      float mz = R6 * sx + R7 * sy + R8 * sz + T2;
      float d2 = (rx * rx + ry * ry + rz * rz) + (mx * mx + my * my + mz * mz)
               - 2.0f * (rx * mx + ry * my + rz * mz);
      float w_ = (d2 < RAD2) ? S.w : 0.0f;            // branchless gate (w=0 pads drop out)
      float wsx = w_ * sx, wsy = w_ * sy, wsz = w_ * sz;
      la[0]  += w_;
      la[1]  += w_ * rx;  la[2]  += w_ * ry;  la[3]  += w_ * rz;
      la[4]  += wsx;      la[5]  += wsy;      la[6]  += wsz;
      la[7]  += wsx * rx; la[8]  += wsx * ry; la[9]  += wsx * rz;
      la[10] += wsy * rx; la[11] += wsy * ry; la[12] += wsy * rz;
      la[13] += wsz * rx; la[14] += wsz * ry; la[15] += wsz * rz;
    }
#pragma unroll
    for (int q = 0; q < 16; q++) {
      float v = la[q];
      for (int off = 32; off > 0; off >>= 1) v += __shfl_down(v, off);
      if (lane == 0) wsum[q][wid] = (double)v;
    }
    __syncthreads();
    if (tid < 16) {
      double s = 0;
      for (int k = 0; k < 16; k++) s += wsum[tid][k];
      acc[tid] = s;
    }
    __syncthreads();
    if (tid == 0) {
      float Rf[9], tf[3];
      solve_rigid(acc, Rf, tf);
      for (int i = 0; i < 9; i++) sR[i] = Rf[i];
      for (int i = 0; i < 3; i++) sT[i] = tf[i];
    }
    __syncthreads();
  }

  if (tid == 0) {
    outT[0] = sR[0]; outT[1] = sR[1]; outT[2]  = sR[2]; outT[3]  = sT[0];
    outT[4] = sR[3]; outT[5] = sR[4]; outT[6]  = sR[5]; outT[7]  = sT[1];
    outT[8] = sR[6]; outT[9] = sR[7]; outT[10] = sR[8]; outT[11] = sT[2];
    outT[12] = 0.0f; outT[13] = 0.0f; outT[14] = 0.0f; outT[15] = 1.0f;
  }
}

extern "C" void kernel_launch(void* const* d_in, const int* in_sizes, int n_in,
                              void* d_out, int out_size, void* d_ws, size_t ws_size,
                              hipStream_t stream) {
  const float* ref   = (const float*)d_in[0];
  const float* src   = (const float*)d_in[1];
  const float* score = (const float*)d_in[2];
  float* w    = (float*)d_out;
  float* outT = (float*)d_out + (size_t)NB * NM * NN;
  Ws* ws = (Ws*)d_ws;

  kA<<<NB, 256, 0, stream>>>(ref, src, score, w, ws);
  kB<<<NB, 256, 0, stream>>>(ws);
  kC<<<1, 1024, 0, stream>>>(outT, ws);
}

// Round 14
// 199.928 us; speedup vs baseline: 2.3105x; 1.0173x over previous
//
#include <hip/hip_runtime.h>
#include <math.h>

#define NB 128
#define NM 64
#define NN 64
#define KSEL 3
#define SLOTS (NM * KSEL)          // 192
#define TOTSLOTS (NB * SLOTS)      // 24576
#define CONF_TH 0.05f
#define RAD2 0.01f                 // ACCEPTANCE_RADIUS^2
#define EPSV 1e-5
#define CBLK 48                    // kC grid: 48 x 512 = 24576 = one thread per slot
#define CTHR 512

// Slot = {src.xyz, w} + {ref.xyz, pad} resolved at kA time. One 32B line per
// correspondence: kB/kC read 2 coalesced dwordx4, zero index math, no gather.
struct Slot {
  float4 s;   // sx, sy, sz, w
  float4 r;   // rx, ry, rz, 0
};

struct Ws {
  Slot   pack[TOTSLOTS];   // 768 KB
  float  Rb[NB * 9];
  float  tb[NB * 3];
  int    ncorr[NB];
  int    bestkey;
  int    bar_cnt;          // grid-barrier state (init by kA block 0)
  int    bar_gen;
  double partial[CBLK][16];// per-block f64 partials (agent-scope traffic)
  float  cur[12];          // R(9) + t(3) broadcast between iterations
};

__device__ __forceinline__ void mat3vec(const double H[3][3], const double v[3], double o[3]) {
  o[0] = H[0][0] * v[0] + H[0][1] * v[1] + H[0][2] * v[2];
  o[1] = H[1][0] * v[0] + H[1][1] * v[1] + H[1][2] * v[2];
  o[2] = H[2][0] * v[0] + H[2][1] * v[1] + H[2][2] * v[2];
}

__device__ __forceinline__ void cross3(const double a[3], const double b[3], double o[3]) {
  o[0] = a[1] * b[2] - a[2] * b[1];
  o[1] = a[2] * b[0] - a[0] * b[2];
  o[2] = a[0] * b[1] - a[1] * b[0];
}

// acc[0]=S, acc[1..3]=Sum(w*ref), acc[4..6]=Sum(w*src), acc[7+c*3+d]=Sum(w*src_c*ref_d)
// Reproduces: wn = w/(S+eps); H = Sum wn (src-cs)(ref-cr)^T; H=USV^T; R=V diag(1,1,det) U^T
__device__ void solve_rigid(const double* acc, float* Rf, float* tf) {
  double denom = acc[0] + EPSV;
  double cr[3], cs[3];
  for (int i = 0; i < 3; i++) { cr[i] = acc[1 + i] / denom; cs[i] = acc[4 + i] / denom; }
  double sig = acc[0] / denom;
  double H[3][3];
  for (int c = 0; c < 3; c++)
    for (int d = 0; d < 3; d++)
      H[c][d] = acc[7 + c * 3 + d] / denom - (2.0 - sig) * cs[c] * cr[d];

  // A = H^T H (symmetric PSD, in ref-space)
  double A[3][3], V[3][3] = {{1,0,0},{0,1,0},{0,0,1}};
  for (int i = 0; i < 3; i++)
    for (int j = 0; j < 3; j++) {
      double s = 0;
      for (int k = 0; k < 3; k++) s += H[k][i] * H[k][j];
      A[i][j] = s;
    }
  // Cyclic Jacobi; relative early-skip makes converged sweeps ~free.
  for (int sweep = 0; sweep < 15; sweep++) {
    for (int p = 0; p < 3; p++) {
      for (int q = p + 1; q < 3; q++) {
        double apq = A[p][q];
        if (fabs(apq) <= 1e-14 * (fabs(A[p][p]) + fabs(A[q][q]))) continue;
        double tau = (A[q][q] - A[p][p]) / (2.0 * apq);
        double tt = (tau >= 0.0) ? 1.0 / (tau + sqrt(1.0 + tau * tau))
                                 : 1.0 / (tau - sqrt(1.0 + tau * tau));
        double c = 1.0 / sqrt(1.0 + tt * tt), s = tt * c;
        for (int k = 0; k < 3; k++) {      // A <- A*J
          double akp = A[k][p], akq = A[k][q];
          A[k][p] = c * akp - s * akq;
          A[k][q] = s * akp + c * akq;
        }
        for (int k = 0; k < 3; k++) {      // A <- J^T*A
          double apk = A[p][k], aqk = A[q][k];
          A[p][k] = c * apk - s * aqk;
          A[q][k] = s * apk + c * aqk;
        }
        for (int k = 0; k < 3; k++) {      // V <- V*J
          double vkp = V[k][p], vkq = V[k][q];
          V[k][p] = c * vkp - s * vkq;
          V[k][q] = s * vkp + c * vkq;
        }
      }
    }
  }
  double lam[3] = {A[0][0], A[1][1], A[2][2]};
  int i0 = 0, i1 = 1, i2 = 2, tmp;
  if (lam[i0] < lam[i1]) { tmp = i0; i0 = i1; i1 = tmp; }
  if (lam[i0] < lam[i2]) { tmp = i0; i0 = i2; i2 = tmp; }
  if (lam[i1] < lam[i2]) { tmp = i1; i1 = i2; i2 = tmp; }

  double v1[3] = {V[0][i0], V[1][i0], V[2][i0]};
  double v2[3] = {V[0][i1], V[1][i1], V[2][i1]};
  double u1[3], u2[3];
  mat3vec(H, v1, u1);
  double n1 = sqrt(u1[0]*u1[0] + u1[1]*u1[1] + u1[2]*u1[2]);
  if (n1 > 1e-30) { u1[0] /= n1; u1[1] /= n1; u1[2] /= n1; }
  else { u1[0] = 1; u1[1] = 0; u1[2] = 0; }
  mat3vec(H, v2, u2);
  double d12 = u1[0]*u2[0] + u1[1]*u2[1] + u1[2]*u2[2];
  u2[0] -= d12 * u1[0]; u2[1] -= d12 * u1[1]; u2[2] -= d12 * u1[2];
  double n2 = sqrt(u2[0]*u2[0] + u2[1]*u2[1] + u2[2]*u2[2]);
  if (n2 > 1e-30) { u2[0] /= n2; u2[1] /= n2; u2[2] /= n2; }
  else {
    double ax[3] = { (fabs(u1[0]) < 0.9) ? 1.0 : 0.0, (fabs(u1[0]) < 0.9) ? 0.0 : 1.0, 0.0 };
    cross3(u1, ax, u2);
    double nn = sqrt(u2[0]*u2[0] + u2[1]*u2[1] + u2[2]*u2[2]);
    u2[0] /= nn; u2[1] /= nn; u2[2] /= nn;
  }
  double u3[3], v3[3];
  cross3(u1, u2, u3);
  cross3(v1, v2, v3);
  double Rd[3][3];
  for (int i = 0; i < 3; i++)
    for (int j = 0; j < 3; j++)
      Rd[i][j] = v1[i] * u1[j] + v2[i] * u2[j] + v3[i] * u3[j];
  for (int i = 0; i < 3; i++) {
    double t = cr[i] - (Rd[i][0] * cs[0] + Rd[i][1] * cs[1] + Rd[i][2] * cs[2]);
    tf[i] = (float)t;
    for (int j = 0; j < 3; j++) Rf[i * 3 + j] = (float)Rd[i][j];
  }
}

// Count+generation grid barrier; generation read BEFORE count-add (classic safe
// ordering). Partials use agent-scope atomics so cross-XCD L2 non-coherence (G16)
// cannot serve stale data. Deadlock-safe: 48 blocks x 8 waves << machine capacity.
__device__ __forceinline__ void gbar(int* cnt, int* gen) {
  __syncthreads();   // drains each thread's stores (vmcnt 0) before signaling
  if (threadIdx.x == 0) {
    int g = __hip_atomic_load(gen, __ATOMIC_RELAXED, __HIP_MEMORY_SCOPE_AGENT);
    __threadfence();
    int old = __hip_atomic_fetch_add(cnt, 1, __ATOMIC_ACQ_REL, __HIP_MEMORY_SCOPE_AGENT);
    if (old == CBLK - 1) {
      __hip_atomic_store(cnt, 0, __ATOMIC_RELAXED, __HIP_MEMORY_SCOPE_AGENT);
      __threadfence();
      __hip_atomic_fetch_add(gen, 1, __ATOMIC_ACQ_REL, __HIP_MEMORY_SCOPE_AGENT);
    } else {
      while (__hip_atomic_load(gen, __ATOMIC_ACQUIRE, __HIP_MEMORY_SCOPE_AGENT) == g)
        __builtin_amdgcn_s_sleep(1);
    }
  }
  __syncthreads();
}

// ---------------- kernel A: exp + mutual top-3 + w + packed corr + per-patch Procrustes ---
__global__ __launch_bounds__(256) void kA(const float* __restrict__ ref,
                                          const float* __restrict__ src,
                                          const float* __restrict__ score,
                                          float* __restrict__ wout,
                                          Ws* __restrict__ ws) {
  const int b = blockIdx.x;
  const int tid = threadIdx.x;
  __shared__ float se[NM][NN + 1];             // +1 pad: row scan (256B stride) conflict-free
  __shared__ unsigned long long rowmask[NM], colmask[NN];
  __shared__ int rsel[NM][KSEL];
  __shared__ float red[16][SLOTS + 1];         // +1 pad: 16-lane column reduce conflict-free
  __shared__ double acc[16];
  __shared__ int scount;

  const float* sc = score + (size_t)b * NM * NN;
  for (int i = tid; i < NM * NN; i += 256)
    se[i >> 6][i & 63] = expf(sc[i]);
  if (tid == 0) scount = 0;
  __syncthreads();

  if (tid < NM) {                               // top-3 per row m (over n)
    const int m = tid;
    float v0 = -1e30f, v1 = -1e30f, v2 = -1e30f; int j0 = 0, j1 = 0, j2 = 0;
    for (int n = 0; n < NN; n++) {
      float v = se[m][n];
      if (v > v0) { v2 = v1; j2 = j1; v1 = v0; j1 = j0; v0 = v; j0 = n; }
      else if (v > v1) { v2 = v1; j2 = j1; v1 = v; j1 = n; }
      else if (v > v2) { v2 = v; j2 = n; }
    }
    rsel[m][0] = j0; rsel[m][1] = j1; rsel[m][2] = j2;
    rowmask[m] = (1ull << j0) | (1ull << j1) | (1ull << j2);
  } else if (tid < 128) {                       // top-3 per column n (over m)
    const int n = tid - 64;
    float v0 = -1e30f, v1 = -1e30f, v2 = -1e30f; int j0 = 0, j1 = 0, j2 = 0;
    for (int m = 0; m < NM; m++) {
      float v = se[m][n];
      if (v > v0) { v2 = v1; j2 = j1; v1 = v0; j1 = j0; v0 = v; j0 = m; }
      else if (v > v1) { v2 = v1; j2 = j1; v1 = v; j1 = m; }
      else if (v > v2) { v2 = v; j2 = m; }
    }
    colmask[n] = (1ull << j0) | (1ull << j1) | (1ull << j2);
  }
  __syncthreads();

  // dense w output
  float* wo = wout + (size_t)b * NM * NN;
  for (int i = tid; i < NM * NN; i += 256) {
    int m = i >> 6, n = i & 63;
    float e = se[m][n];
    bool corr = ((rowmask[m] >> n) & 1ull) && ((colmask[n] >> m) & 1ull) && (e > CONF_TH);
    wo[i] = corr ? e : 0.0f;
  }

  // packed slots (m,k) -> {src,w}+{ref}; and per-slot Procrustes partials
  if (tid < SLOTS) {
    int m = tid / 3;
    int k = tid - m * 3;
    int n = rsel[m][k];
    float e = se[m][n];
    bool corr = ((colmask[n] >> m) & 1ull) && (e > CONF_TH);
    float cw = corr ? e : 0.0f;
    float rx = ref[((size_t)b * NM + m) * 3 + 0];
    float ry = ref[((size_t)b * NM + m) * 3 + 1];
    float rz = ref[((size_t)b * NM + m) * 3 + 2];
    float sx = src[((size_t)b * NN + n) * 3 + 0];
    float sy = src[((size_t)b * NN + n) * 3 + 1];
    float sz = src[((size_t)b * NN + n) * 3 + 2];
    ws->pack[b * SLOTS + tid].s = make_float4(sx, sy, sz, cw);
    ws->pack[b * SLOTS + tid].r = make_float4(rx, ry, rz, 0.0f);
    if (corr) atomicAdd(&scount, 1);
    red[0][tid] = cw;
    red[1][tid] = cw * rx;  red[2][tid] = cw * ry;  red[3][tid] = cw * rz;
    red[4][tid] = cw * sx;  red[5][tid] = cw * sy;  red[6][tid] = cw * sz;
    red[7][tid]  = cw * sx * rx; red[8][tid]  = cw * sx * ry; red[9][tid]  = cw * sx * rz;
    red[10][tid] = cw * sy * rx; red[11][tid] = cw * sy * ry; red[12][tid] = cw * sy * rz;
    red[13][tid] = cw * sz * rx; red[14][tid] = cw * sz * ry; red[15][tid] = cw * sz * rz;
  }
  __syncthreads();
  if (tid < 16) {
    double s = 0;
    for (int i = 0; i < SLOTS; i++) s += (double)red[tid][i];
    acc[tid] = s;
  }
  __syncthreads();
  if (tid == 0) {
    float Rf[9], tf[3];
    solve_rigid(acc, Rf, tf);
    for (int i = 0; i < 9; i++) ws->Rb[b * 9 + i] = Rf[i];
    for (int i = 0; i < 3; i++) ws->tb[b * 3 + i] = tf[i];
    ws->ncorr[b] = scount;
    if (b == 0) { ws->bestkey = 0; ws->bar_cnt = 0; ws->bar_gen = 0; }
  }
}

// ---------------- kernel B: verify candidate p over all correspondences (packed stream) ---
__global__ __launch_bounds__(256) void kB(Ws* __restrict__ ws) {
  const int p = blockIdx.x;
  const int tid = threadIdx.x;
  float R[9], T[3];
#pragma unroll
  for (int i = 0; i < 9; i++) R[i] = ws->Rb[p * 9 + i];
#pragma unroll
  for (int i = 0; i < 3; i++) T[i] = ws->tb[p * 3 + i];

  int cnt = 0;
  for (int g = tid; g < TOTSLOTS; g += 256) {
    float4 S = ws->pack[g].s;
    float4 Rv = ws->pack[g].r;
    float sx = S.x, sy = S.y, sz = S.z;
    float rx = Rv.x, ry = Rv.y, rz = Rv.z;
    float mx = R[0] * sx + R[1] * sy + R[2] * sz + T[0];
    float my = R[3] * sx + R[4] * sy + R[5] * sz + T[1];
    float mz = R[6] * sx + R[7] * sy + R[8] * sz + T[2];
    float d2 = (rx * rx + ry * ry + rz * rz) + (mx * mx + my * my + mz * mz)
             - 2.0f * (rx * mx + ry * my + rz * mz);
    cnt += (S.w > 0.0f && d2 < RAD2) ? 1 : 0;
  }
  __shared__ int sred[256];
  sred[tid] = cnt;
  __syncthreads();
  for (int s = 128; s > 0; s >>= 1) {
    if (tid < s) sred[tid] += sred[tid + s];
    __syncthreads();
  }
  if (tid == 0) {
    int c = (ws->ncorr[p] >= 3) ? sred[0] : -1;
    int key = ((c + 1) << 8) | (127 - p);   // ties -> smaller p wins (first-index argmax)
    atomicMax(&ws->bestkey, key);
  }
}

// ---------------- kernel C: persistent 48-block refinement, slot-in-register -------------
// One thread owns one slot for all 5 iterations (pack read from L2 exactly once).
// Per iter: f32 products -> wave shfl tree -> LDS -> f64 block partial -> grid barrier ->
// block 0 gathers + solves (f64) -> broadcasts R,t -> barrier. All inter-block data via
// agent-scope atomics (cross-XCD coherent).
__global__ __launch_bounds__(CTHR) void kC(float* __restrict__ outT,
                                           Ws* __restrict__ ws) {
  const int tid = threadIdx.x, bid = blockIdx.x;
  const int lane = tid & 63, wid = tid >> 6;    // 8 waves
  __shared__ double lred[16][CTHR / 64];        // [quantity][wave]
  __shared__ double accs[16];
  __shared__ float sRt[12];

  const int g = bid * CTHR + tid;               // exactly one slot per thread
  const float4 S  = ws->pack[g].s;
  const float4 Rv = ws->pack[g].r;
  const float sx = S.x, sy = S.y, sz = S.z, w0 = S.w;
  const float rx = Rv.x, ry = Rv.y, rz = Rv.z;
  const float rr = rx * rx + ry * ry + rz * rz;

  for (int iter = 0; iter < 5; iter++) {
    float Rm[12];
    if (iter == 0) {                            // best candidate (kB result, plain loads OK
      int p = 127 - (ws->bestkey & 0xFF);       //  across kernel boundary)
#pragma unroll
      for (int i = 0; i < 9; i++) Rm[i] = ws->Rb[p * 9 + i];
#pragma unroll
      for (int i = 0; i < 3; i++) Rm[9 + i] = ws->tb[p * 3 + i];
    } else {                                    // broadcast from block 0's solve
#pragma unroll
      for (int i = 0; i < 12; i++)
        Rm[i] = __hip_atomic_load(&ws->cur[i], __ATOMIC_RELAXED, __HIP_MEMORY_SCOPE_AGENT);
    }

    float mx = Rm[0] * sx + Rm[1] * sy + Rm[2] * sz + Rm[9];
    float my = Rm[3] * sx + Rm[4] * sy + Rm[5] * sz + Rm[10];
    float mz = Rm[6] * sx + Rm[7] * sy + Rm[8] * sz + Rm[11];
    float d2 = rr + (mx * mx + my * my + mz * mz)
             - 2.0f * (rx * mx + ry * my + rz * mz);
    float w_ = (d2 < RAD2) ? w0 : 0.0f;         // branchless gate (w=0 pads drop out)
    float wsx = w_ * sx, wsy = w_ * sy, wsz = w_ * sz;
    float la[16];
    la[0] = w_;
    la[1] = w_ * rx;  la[2] = w_ * ry;  la[3] = w_ * rz;
    la[4] = wsx;      la[5] = wsy;      la[6] = wsz;
    la[7]  = wsx * rx; la[8]  = wsx * ry; la[9]  = wsx * rz;
    la[10] = wsy * rx; la[11] = wsy * ry; la[12] = wsy * rz;
    la[13] = wsz * rx; la[14] = wsz * ry; la[15] = wsz * rz;

#pragma unroll
    for (int q = 0; q < 16; q++) {
      float v = la[q];
      for (int off = 32; off > 0; off >>= 1) v += __shfl_down(v, off);
      if (lane == 0) lred[q][wid] = (double)v;
    }
    __syncthreads();
    if (tid < 16) {
      double s = 0;
#pragma unroll
      for (int k = 0; k < CTHR / 64; k++) s += lred[tid][k];
      __hip_atomic_store(&ws->partial[bid][tid], s, __ATOMIC_RELAXED, __HIP_MEMORY_SCOPE_AGENT);
    }
    gbar(&ws->bar_cnt, &ws->bar_gen);

    if (bid == 0) {
      if (tid < 16) {
        double s = 0;
        for (int k = 0; k < CBLK; k++)
          s += __hip_atomic_load(&ws->partial[k][tid], __ATOMIC_RELAXED, __HIP_MEMORY_SCOPE_AGENT);
        accs[tid] = s;
      }
      __syncthreads();
      if (tid == 0) {
        float Rf[9], tf[3];
        solve_rigid(accs, Rf, tf);
#pragma unroll
        for (int i = 0; i < 9; i++) sRt[i] = Rf[i];
#pragma unroll
        for (int i = 0; i < 3; i++) sRt[9 + i] = tf[i];
        if (iter < 4) {
#pragma unroll
          for (int i = 0; i < 12; i++)
            __hip_atomic_store(&ws->cur[i], sRt[i], __ATOMIC_RELAXED, __HIP_MEMORY_SCOPE_AGENT);
        }
      }
      __syncthreads();
    }
    if (iter < 4) gbar(&ws->bar_cnt, &ws->bar_gen);   // uniform across all blocks
  }

  if (bid == 0 && tid == 0) {
    outT[0] = sRt[0]; outT[1] = sRt[1]; outT[2]  = sRt[2]; outT[3]  = sRt[9];
    outT[4] = sRt[3]; outT[5] = sRt[4]; outT[6]  = sRt[5]; outT[7]  = sRt[10];
    outT[8] = sRt[6]; outT[9] = sRt[7]; outT[10] = sRt[8]; outT[11] = sRt[11];
    outT[12] = 0.0f; outT[13] = 0.0f; outT[14] = 0.0f; outT[15] = 1.0f;
  }
}

extern "C" void kernel_launch(void* const* d_in, const int* in_sizes, int n_in,
                              void* d_out, int out_size, void* d_ws, size_t ws_size,
                              hipStream_t stream) {
  const float* ref   = (const float*)d_in[0];
  const float* src   = (const float*)d_in[1];
  const float* score = (const float*)d_in[2];
  float* w    = (float*)d_out;
  float* outT = (float*)d_out + (size_t)NB * NM * NN;
  Ws* ws = (Ws*)d_ws;

  kA<<<NB, 256, 0, stream>>>(ref, src, score, w, ws);
  kB<<<NB, 256, 0, stream>>>(ws);
  kC<<<CBLK, CTHR, 0, stream>>>(outT, ws);
}

// Round 15
// 174.956 us; speedup vs baseline: 2.6403x; 1.1427x over previous
//
#include <hip/hip_runtime.h>
#include <math.h>

#define NB 128
#define NM 64
#define NN 64
#define KSEL 3
#define SLOTS (NM * KSEL)          // 192
#define TOTSLOTS (NB * SLOTS)      // 24576
#define CONF_TH 0.05f
#define RAD2 0.01f                 // ACCEPTANCE_RADIUS^2
#define EPSV 1e-5
#define CBLK 48                    // kCiter grid: 48 x 512 = 24576 = one thread per slot
#define CTHR 512
#define ITERS 5

// Slot = {src.xyz, w} + {ref.xyz, pad} resolved at kA time. One 32B line per
// correspondence: kB/kC read 2 coalesced dwordx4, zero index math, no gather.
struct Slot {
  float4 s;   // sx, sy, sz, w
  float4 r;   // rx, ry, rz, 0
};

struct Ws {
  Slot   pack[TOTSLOTS];    // 768 KB
  float  Rb[NB * 9];
  float  tb[NB * 3];
  int    ncorr[NB];
  int    bestkey;
  int    ticket[ITERS];     // per-iteration last-block tickets (zeroed by kA)
  double partial[CBLK][16]; // per-block f64 partials
  float  cur[12];           // R(9)+t(3) handoff between iteration launches
};

__device__ __forceinline__ void mat3vec(const double H[3][3], const double v[3], double o[3]) {
  o[0] = H[0][0] * v[0] + H[0][1] * v[1] + H[0][2] * v[2];
  o[1] = H[1][0] * v[0] + H[1][1] * v[1] + H[1][2] * v[2];
  o[2] = H[2][0] * v[0] + H[2][1] * v[1] + H[2][2] * v[2];
}

__device__ __forceinline__ void cross3(const double a[3], const double b[3], double o[3]) {
  o[0] = a[1] * b[2] - a[2] * b[1];
  o[1] = a[2] * b[0] - a[0] * b[2];
  o[2] = a[0] * b[1] - a[1] * b[0];
}

// acc[0]=S, acc[1..3]=Sum(w*ref), acc[4..6]=Sum(w*src), acc[7+c*3+d]=Sum(w*src_c*ref_d)
// Reproduces: wn = w/(S+eps); H = Sum wn (src-cs)(ref-cr)^T; H=USV^T; R=V diag(1,1,det) U^T
__device__ void solve_rigid(const double* acc, float* Rf, float* tf) {
  double denom = acc[0] + EPSV;
  double cr[3], cs[3];
  for (int i = 0; i < 3; i++) { cr[i] = acc[1 + i] / denom; cs[i] = acc[4 + i] / denom; }
  double sig = acc[0] / denom;
  double H[3][3];
  for (int c = 0; c < 3; c++)
    for (int d = 0; d < 3; d++)
      H[c][d] = acc[7 + c * 3 + d] / denom - (2.0 - sig) * cs[c] * cr[d];

  // A = H^T H (symmetric PSD, in ref-space)
  double A[3][3], V[3][3] = {{1,0,0},{0,1,0},{0,0,1}};
  for (int i = 0; i < 3; i++)
    for (int j = 0; j < 3; j++) {
      double s = 0;
      for (int k = 0; k < 3; k++) s += H[k][i] * H[k][j];
      A[i][j] = s;
    }
  // Cyclic Jacobi; relative early-skip makes converged sweeps ~free.
  for (int sweep = 0; sweep < 15; sweep++) {
    for (int p = 0; p < 3; p++) {
      for (int q = p + 1; q < 3; q++) {
        double apq = A[p][q];
        if (fabs(apq) <= 1e-14 * (fabs(A[p][p]) + fabs(A[q][q]))) continue;
        double tau = (A[q][q] - A[p][p]) / (2.0 * apq);
        double tt = (tau >= 0.0) ? 1.0 / (tau + sqrt(1.0 + tau * tau))
                                 : 1.0 / (tau - sqrt(1.0 + tau * tau));
        double c = 1.0 / sqrt(1.0 + tt * tt), s = tt * c;
        for (int k = 0; k < 3; k++) {      // A <- A*J
          double akp = A[k][p], akq = A[k][q];
          A[k][p] = c * akp - s * akq;
          A[k][q] = s * akp + c * akq;
        }
        for (int k = 0; k < 3; k++) {      // A <- J^T*A
          double apk = A[p][k], aqk = A[q][k];
          A[p][k] = c * apk - s * aqk;
          A[q][k] = s * apk + c * aqk;
        }
        for (int k = 0; k < 3; k++) {      // V <- V*J
          double vkp = V[k][p], vkq = V[k][q];
          V[k][p] = c * vkp - s * vkq;
          V[k][q] = s * vkp + c * vkq;
        }
      }
    }
  }
  double lam[3] = {A[0][0], A[1][1], A[2][2]};
  int i0 = 0, i1 = 1, i2 = 2, tmp;
  if (lam[i0] < lam[i1]) { tmp = i0; i0 = i1; i1 = tmp; }
  if (lam[i0] < lam[i2]) { tmp = i0; i0 = i2; i2 = tmp; }
  if (lam[i1] < lam[i2]) { tmp = i1; i1 = i2; i2 = tmp; }

  double v1[3] = {V[0][i0], V[1][i0], V[2][i0]};
  double v2[3] = {V[0][i1], V[1][i1], V[2][i1]};
  double u1[3], u2[3];
  mat3vec(H, v1, u1);
  double n1 = sqrt(u1[0]*u1[0] + u1[1]*u1[1] + u1[2]*u1[2]);
  if (n1 > 1e-30) { u1[0] /= n1; u1[1] /= n1; u1[2] /= n1; }
  else { u1[0] = 1; u1[1] = 0; u1[2] = 0; }
  mat3vec(H, v2, u2);
  double d12 = u1[0]*u2[0] + u1[1]*u2[1] + u1[2]*u2[2];
  u2[0] -= d12 * u1[0]; u2[1] -= d12 * u1[1]; u2[2] -= d12 * u1[2];
  double n2 = sqrt(u2[0]*u2[0] + u2[1]*u2[1] + u2[2]*u2[2]);
  if (n2 > 1e-30) { u2[0] /= n2; u2[1] /= n2; u2[2] /= n2; }
  else {
    double ax[3] = { (fabs(u1[0]) < 0.9) ? 1.0 : 0.0, (fabs(u1[0]) < 0.9) ? 0.0 : 1.0, 0.0 };
    cross3(u1, ax, u2);
    double nn = sqrt(u2[0]*u2[0] + u2[1]*u2[1] + u2[2]*u2[2]);
    u2[0] /= nn; u2[1] /= nn; u2[2] /= nn;
  }
  double u3[3], v3[3];
  cross3(u1, u2, u3);
  cross3(v1, v2, v3);
  double Rd[3][3];
  for (int i = 0; i < 3; i++)
    for (int j = 0; j < 3; j++)
      Rd[i][j] = v1[i] * u1[j] + v2[i] * u2[j] + v3[i] * u3[j];
  for (int i = 0; i < 3; i++) {
    double t = cr[i] - (Rd[i][0] * cs[0] + Rd[i][1] * cs[1] + Rd[i][2] * cs[2]);
    tf[i] = (float)t;
    for (int j = 0; j < 3; j++) Rf[i * 3 + j] = (float)Rd[i][j];
  }
}

// ---------------- kernel A: exp + mutual top-3 + w + packed corr + per-patch Procrustes ---
__global__ __launch_bounds__(256) void kA(const float* __restrict__ ref,
                                          const float* __restrict__ src,
                                          const float* __restrict__ score,
                                          float* __restrict__ wout,
                                          Ws* __restrict__ ws) {
  const int b = blockIdx.x;
  const int tid = threadIdx.x;
  __shared__ float se[NM][NN + 1];             // +1 pad: row scan (256B stride) conflict-free
  __shared__ unsigned long long rowmask[NM], colmask[NN];
  __shared__ int rsel[NM][KSEL];
  __shared__ float red[16][SLOTS + 1];         // +1 pad: 16-lane column reduce conflict-free
  __shared__ double acc[16];
  __shared__ int scount;

  const float* sc = score + (size_t)b * NM * NN;
  for (int i = tid; i < NM * NN; i += 256)
    se[i >> 6][i & 63] = expf(sc[i]);
  if (tid == 0) scount = 0;
  __syncthreads();

  if (tid < NM) {                               // top-3 per row m (over n)
    const int m = tid;
    float v0 = -1e30f, v1 = -1e30f, v2 = -1e30f; int j0 = 0, j1 = 0, j2 = 0;
    for (int n = 0; n < NN; n++) {
      float v = se[m][n];
      if (v > v0) { v2 = v1; j2 = j1; v1 = v0; j1 = j0; v0 = v; j0 = n; }
      else if (v > v1) { v2 = v1; j2 = j1; v1 = v; j1 = n; }
      else if (v > v2) { v2 = v; j2 = n; }
    }
    rsel[m][0] = j0; rsel[m][1] = j1; rsel[m][2] = j2;
    rowmask[m] = (1ull << j0) | (1ull << j1) | (1ull << j2);
  } else if (tid < 128) {                       // top-3 per column n (over m)
    const int n = tid - 64;
    float v0 = -1e30f, v1 = -1e30f, v2 = -1e30f; int j0 = 0, j1 = 0, j2 = 0;
    for (int m = 0; m < NM; m++) {
      float v = se[m][n];
      if (v > v0) { v2 = v1; j2 = j1; v1 = v0; j1 = j0; v0 = v; j0 = m; }
      else if (v > v1) { v2 = v1; j2 = j1; v1 = v; j1 = m; }
      else if (v > v2) { v2 = v; j2 = m; }
    }
    colmask[n] = (1ull << j0) | (1ull << j1) | (1ull << j2);
  }
  __syncthreads();

  // dense w output
  float* wo = wout + (size_t)b * NM * NN;
  for (int i = tid; i < NM * NN; i += 256) {
    int m = i >> 6, n = i & 63;
    float e = se[m][n];
    bool corr = ((rowmask[m] >> n) & 1ull) && ((colmask[n] >> m) & 1ull) && (e > CONF_TH);
    wo[i] = corr ? e : 0.0f;
  }

  // packed slots (m,k) -> {src,w}+{ref}; and per-slot Procrustes partials
  if (tid < SLOTS) {
    int m = tid / 3;
    int k = tid - m * 3;
    int n = rsel[m][k];
    float e = se[m][n];
    bool corr = ((colmask[n] >> m) & 1ull) && (e > CONF_TH);
    float cw = corr ? e : 0.0f;
    float rx = ref[((size_t)b * NM + m) * 3 + 0];
    float ry = ref[((size_t)b * NM + m) * 3 + 1];
    float rz = ref[((size_t)b * NM + m) * 3 + 2];
    float sx = src[((size_t)b * NN + n) * 3 + 0];
    float sy = src[((size_t)b * NN + n) * 3 + 1];
    float sz = src[((size_t)b * NN + n) * 3 + 2];
    ws->pack[b * SLOTS + tid].s = make_float4(sx, sy, sz, cw);
    ws->pack[b * SLOTS + tid].r = make_float4(rx, ry, rz, 0.0f);
    if (corr) atomicAdd(&scount, 1);
    red[0][tid] = cw;
    red[1][tid] = cw * rx;  red[2][tid] = cw * ry;  red[3][tid] = cw * rz;
    red[4][tid] = cw * sx;  red[5][tid] = cw * sy;  red[6][tid] = cw * sz;
    red[7][tid]  = cw * sx * rx; red[8][tid]  = cw * sx * ry; red[9][tid]  = cw * sx * rz;
    red[10][tid] = cw * sy * rx; red[11][tid] = cw * sy * ry; red[12][tid] = cw * sy * rz;
    red[13][tid] = cw * sz * rx; red[14][tid] = cw * sz * ry; red[15][tid] = cw * sz * rz;
  }
  __syncthreads();
  if (tid < 16) {
    double s = 0;
    for (int i = 0; i < SLOTS; i++) s += (double)red[tid][i];
    acc[tid] = s;
  }
  __syncthreads();
  if (tid == 0) {
    float Rf[9], tf[3];
    solve_rigid(acc, Rf, tf);
    for (int i = 0; i < 9; i++) ws->Rb[b * 9 + i] = Rf[i];
    for (int i = 0; i < 3; i++) ws->tb[b * 3 + i] = tf[i];
    ws->ncorr[b] = scount;
    if (b == 0) {
      ws->bestkey = 0;
      for (int i = 0; i < ITERS; i++) ws->ticket[i] = 0;
    }
  }
}

// ---------------- kernel B: verify candidate p over all correspondences (packed stream) ---
__global__ __launch_bounds__(256) void kB(Ws* __restrict__ ws) {
  const int p = blockIdx.x;
  const int tid = threadIdx.x;
  float R[9], T[3];
#pragma unroll
  for (int i = 0; i < 9; i++) R[i] = ws->Rb[p * 9 + i];
#pragma unroll
  for (int i = 0; i < 3; i++) T[i] = ws->tb[p * 3 + i];

  int cnt = 0;
  for (int g = tid; g < TOTSLOTS; g += 256) {
    float4 S = ws->pack[g].s;
    float4 Rv = ws->pack[g].r;
    float sx = S.x, sy = S.y, sz = S.z;
    float rx = Rv.x, ry = Rv.y, rz = Rv.z;
    float mx = R[0] * sx + R[1] * sy + R[2] * sz + T[0];
    float my = R[3] * sx + R[4] * sy + R[5] * sz + T[1];
    float mz = R[6] * sx + R[7] * sy + R[8] * sz + T[2];
    float d2 = (rx * rx + ry * ry + rz * rz) + (mx * mx + my * my + mz * mz)
             - 2.0f * (rx * mx + ry * my + rz * mz);
    cnt += (S.w > 0.0f && d2 < RAD2) ? 1 : 0;
  }
  __shared__ int sred[256];
  sred[tid] = cnt;
  __syncthreads();
  for (int s = 128; s > 0; s >>= 1) {
    if (tid < s) sred[tid] += sred[tid + s];
    __syncthreads();
  }
  if (tid == 0) {
    int c = (ws->ncorr[p] >= 3) ? sred[0] : -1;
    int key = ((c + 1) << 8) | (127 - p);   // ties -> smaller p wins (first-index argmax)
    atomicMax(&ws->bestkey, key);
  }
}

// ---------------- kernel C iteration: one refinement step, kernel boundary = sync --------
// 48 blocks x 512 = one slot/thread. Each block: partial -> release-store -> ticket RMW.
// 47 blocks exit; LAST block gathers 48x16 partials (deterministic order), solves (f64),
// writes cur (next launch reads it) or outT on the final iteration. Replaces the measured
// ~13us/barrier in-kernel grid sync with ~2-3us kernel-boundary sync.
__global__ __launch_bounds__(CTHR) void kCiter(int iter, float* __restrict__ outT,
                                               Ws* __restrict__ ws) {
  const int tid = threadIdx.x, bid = blockIdx.x;
  const int lane = tid & 63, wid = tid >> 6;    // 8 waves
  __shared__ double lred[16][CTHR / 64];
  __shared__ double accs[16];
  __shared__ int amLast;

  const int g = bid * CTHR + tid;               // exactly one slot per thread
  const float4 S  = ws->pack[g].s;
  const float4 Rv = ws->pack[g].r;
  const float sx = S.x, sy = S.y, sz = S.z, w0 = S.w;
  const float rx = Rv.x, ry = Rv.y, rz = Rv.z;

  float Rm[12];
  if (iter == 0) {                              // best candidate from kB (prev kernel)
    int p = 127 - (ws->bestkey & 0xFF);
#pragma unroll
    for (int i = 0; i < 9; i++) Rm[i] = ws->Rb[p * 9 + i];
#pragma unroll
    for (int i = 0; i < 3; i++) Rm[9 + i] = ws->tb[p * 3 + i];
  } else {                                      // cur written by previous launch
#pragma unroll
    for (int i = 0; i < 12; i++) Rm[i] = ws->cur[i];
  }

  float mx = Rm[0] * sx + Rm[1] * sy + Rm[2] * sz + Rm[9];
  float my = Rm[3] * sx + Rm[4] * sy + Rm[5] * sz + Rm[10];
  float mz = Rm[6] * sx + Rm[7] * sy + Rm[8] * sz + Rm[11];
  float d2 = (rx * rx + ry * ry + rz * rz) + (mx * mx + my * my + mz * mz)
           - 2.0f * (rx * mx + ry * my + rz * mz);
  float w_ = (d2 < RAD2) ? w0 : 0.0f;           // branchless gate (w=0 pads drop out)
  float wsx = w_ * sx, wsy = w_ * sy, wsz = w_ * sz;
  float la[16];
  la[0] = w_;
  la[1] = w_ * rx;  la[2] = w_ * ry;  la[3] = w_ * rz;
  la[4] = wsx;      la[5] = wsy;      la[6] = wsz;
  la[7]  = wsx * rx; la[8]  = wsx * ry; la[9]  = wsx * rz;
  la[10] = wsy * rx; la[11] = wsy * ry; la[12] = wsy * rz;
  la[13] = wsz * rx; la[14] = wsz * ry; la[15] = wsz * rz;

#pragma unroll
  for (int q = 0; q < 16; q++) {
    float v = la[q];
    for (int off = 32; off > 0; off >>= 1) v += __shfl_down(v, off);
    if (lane == 0) lred[q][wid] = (double)v;
  }
  __syncthreads();
  if (tid < 16) {
    double s = 0;
#pragma unroll
    for (int k = 0; k < CTHR / 64; k++) s += lred[tid][k];
    __hip_atomic_store(&ws->partial[bid][tid], s, __ATOMIC_RELEASE, __HIP_MEMORY_SCOPE_AGENT);
  }
  __syncthreads();                              // drains stores (vmcnt 0) per wave
  if (tid == 0) {
    int old = __hip_atomic_fetch_add(&ws->ticket[iter], 1, __ATOMIC_ACQ_REL,
                                     __HIP_MEMORY_SCOPE_AGENT);
    amLast = (old == CBLK - 1);                 // RMW chain => all partials visible to last
  }
  __syncthreads();
  if (!amLast) return;                          // 47 blocks exit; no spinning

  if (tid < 16) {
    double s = 0;
    for (int k = 0; k < CBLK; k++)              // deterministic gather order (bit-stable)
      s += __hip_atomic_load(&ws->partial[k][tid], __ATOMIC_RELAXED, __HIP_MEMORY_SCOPE_AGENT);
    accs[tid] = s;
  }
  __syncthreads();
  if (tid == 0) {
    float Rf[9], tf[3];
    solve_rigid(accs, Rf, tf);
    if (iter < ITERS - 1) {
#pragma unroll
      for (int i = 0; i < 9; i++) ws->cur[i] = Rf[i];
#pragma unroll
      for (int i = 0; i < 3; i++) ws->cur[9 + i] = tf[i];
    } else {
      outT[0] = Rf[0]; outT[1] = Rf[1]; outT[2]  = Rf[2]; outT[3]  = tf[0];
      outT[4] = Rf[3]; outT[5] = Rf[4]; outT[6]  = Rf[5]; outT[7]  = tf[1];
      outT[8] = Rf[6]; outT[9] = Rf[7]; outT[10] = Rf[8]; outT[11] = tf[2];
      outT[12] = 0.0f; outT[13] = 0.0f; outT[14] = 0.0f; outT[15] = 1.0f;
    }
  }
}

extern "C" void kernel_launch(void* const* d_in, const int* in_sizes, int n_in,
                              void* d_out, int out_size, void* d_ws, size_t ws_size,
                              hipStream_t stream) {
  const float* ref   = (const float*)d_in[0];
  const float* src   = (const float*)d_in[1];
  const float* score = (const float*)d_in[2];
  float* w    = (float*)d_out;
  float* outT = (float*)d_out + (size_t)NB * NM * NN;
  Ws* ws = (Ws*)d_ws;

  kA<<<NB, 256, 0, stream>>>(ref, src, score, w, ws);
  kB<<<NB, 256, 0, stream>>>(ws);
  for (int it = 0; it < ITERS; ++it)
    kCiter<<<CBLK, CTHR, 0, stream>>>(it, outT, ws);
}